// Round 1
// baseline (292.525 us; speedup 1.0000x reference)
//
#include <hip/hip_runtime.h>
#include <hip/hip_bf16.h>

typedef short v8s __attribute__((ext_vector_type(8)));
typedef float v4f __attribute__((ext_vector_type(4)));

#define LN_EPS 1e-5f
#define EPS_N 1e-3f

__device__ __forceinline__ unsigned short f2bf(float f) {
    __hip_bfloat16 h = __float2bfloat16(f);
    return __builtin_bit_cast(unsigned short, h);
}

// ---------------------------------------------------------------------------
// k0: inv_norm[256][256], wt[64][256] (w1^T|w2^T bf16), w_out_t[128][1024] bf16
//     with permuted contraction index k2'' = (h/4)*128 + k*4 + (h%4)
// ---------------------------------------------------------------------------
__global__ __launch_bounds__(256) void k0_prep(
    const float* __restrict__ mask,
    const float* __restrict__ w1, const float* __restrict__ w2,
    const float* __restrict__ w_out,
    unsigned short* __restrict__ wt,
    unsigned short* __restrict__ w_out_t,
    float* __restrict__ inv_norm) {
    const int b = blockIdx.x, t = threadIdx.x;
    // inv_norm: i = b, j = t
    float acc = 0.f;
    for (int s = 0; s < 128; ++s)
        acc += mask[s * 256 + b] * mask[s * 256 + t];
    inv_norm[b * 256 + t] = 1.0f / (EPS_N + acc);
    // w_out_t: flat index e = z*1024 + k2''
    for (int e2 = 0; e2 < 2; ++e2) {
        int e = b * 512 + e2 * 256 + t;
        int z = e >> 10, k2 = e & 1023;
        int hg = k2 >> 7, k = (k2 >> 2) & 31, hr = k2 & 3;
        int h = hg * 4 + hr;
        w_out_t[e] = f2bf(w_out[(h * 32 + k) * 128 + z]);
    }
    // wt[h2][c]
    if (b == 0) {
        for (int e = t; e < 16384; e += 256) {
            int h2 = e >> 8, c = e & 255;
            float v = (h2 < 32) ? w1[c * 32 + h2] : w2[c * 32 + (h2 - 32)];
            wt[e] = f2bf(v);
        }
    }
}

// ---------------------------------------------------------------------------
// k1: one WG (256 thr) per r. LN over C_S=256, then MFMA [128s x 64h2 x 256c],
// epilogue (+bias)*mask -> a_t[r*32+h][s], b_t[r*32+h][s] bf16.
// ---------------------------------------------------------------------------
__global__ __launch_bounds__(256) void k1_lnproj(
    const float* __restrict__ m, const float* __restrict__ mask,
    const float* __restrict__ ln_w, const float* __restrict__ ln_b,
    const float* __restrict__ b1, const float* __restrict__ b2,
    const unsigned short* __restrict__ wt,
    unsigned short* __restrict__ a_t, unsigned short* __restrict__ b_t) {
    __shared__ unsigned short mh[128 * 256];   // 64 KB, chunk-swizzled
    const int r = blockIdx.x;
    const int tid = threadIdx.x;
    const int w = tid >> 6, l = tid & 63;
    const int quad = l >> 4, l15 = l & 15;

    const float4 lwv = *(const float4*)(ln_w + l * 4);
    const float4 lbv = *(const float4*)(ln_b + l * 4);

    // phase 1: LN rows s = w*32 .. w*32+31 (one row per wave-iteration)
    for (int it = 0; it < 32; ++it) {
        const int s = w * 32 + it;
        const float4 v = *(const float4*)(m + ((s * 256 + r) << 8) + (l << 2));
        float sum = v.x + v.y + v.z + v.w;
        float sq  = v.x * v.x + v.y * v.y + v.z * v.z + v.w * v.w;
        for (int off = 32; off; off >>= 1) {
            sum += __shfl_xor(sum, off);
            sq  += __shfl_xor(sq,  off);
        }
        const float mu   = sum * (1.f / 256.f);
        const float var  = sq * (1.f / 256.f) - mu * mu;
        const float rstd = rsqrtf(var + LN_EPS);
        const float o0 = (v.x - mu) * rstd * lwv.x + lbv.x;
        const float o1 = (v.y - mu) * rstd * lwv.y + lbv.y;
        const float o2 = (v.z - mu) * rstd * lwv.z + lbv.z;
        const float o3 = (v.w - mu) * rstd * lwv.w + lbv.w;
        const unsigned int p0 = (unsigned)f2bf(o0) | ((unsigned)f2bf(o1) << 16);
        const unsigned int p1 = (unsigned)f2bf(o2) | ((unsigned)f2bf(o3) << 16);
        // lane l holds cols 4l..4l+3 -> chunk = l>>1, half = l&1; swizzle chunk^(s&31)
        const int addr = s * 256 + (((l >> 1) ^ (s & 31)) << 3) + ((l & 1) << 2);
        *(uint2*)(&mh[addr]) = make_uint2(p0, p1);
    }
    __syncthreads();

    // phase 2: MFMA. wave w owns m-tiles 2w,2w+1 (rows 32w..32w+31), n-tiles 0..3
    v4f acc[2][4];
    const v4f z4 = {0.f, 0.f, 0.f, 0.f};
    for (int a = 0; a < 2; ++a)
        for (int bn = 0; bn < 4; ++bn) acc[a][bn] = z4;

    for (int kb = 0; kb < 8; ++kb) {
        v8s af[2], bfr[4];
        for (int tm2 = 0; tm2 < 2; ++tm2) {
            const int row = (w * 2 + tm2) * 16 + l15;
            const int chunk = (kb * 4 + quad) ^ (row & 31);
            af[tm2] = *(const v8s*)(&mh[row * 256 + chunk * 8]);
        }
        const int ks = kb * 32 + quad * 8;
        for (int tn = 0; tn < 4; ++tn) {
            const int n = tn * 16 + l15;
            bfr[tn] = *(const v8s*)(wt + n * 256 + ks);
        }
        for (int tm2 = 0; tm2 < 2; ++tm2)
            for (int tn = 0; tn < 4; ++tn)
                acc[tm2][tn] = __builtin_amdgcn_mfma_f32_16x16x32_bf16(
                    af[tm2], bfr[tn], acc[tm2][tn], 0, 0, 0);
    }

    // epilogue: D[s-row][h2]; rows s = (w*2+tm2)*16 + quad*4 + u, col h2 = tn*16+l15
    for (int tm2 = 0; tm2 < 2; ++tm2) {
        const int s0 = (w * 2 + tm2) * 16 + quad * 4;
        float mk[4];
        for (int u = 0; u < 4; ++u) mk[u] = mask[(s0 + u) * 256 + r];
        for (int tn = 0; tn < 4; ++tn) {
            const int h2 = tn * 16 + l15;
            const float bias = (h2 < 32) ? b1[h2] : b2[h2 - 32];
            unsigned short* dst = (h2 < 32) ? a_t : b_t;
            const int h = h2 & 31;
            const v4f f = acc[tm2][tn];
            const unsigned int q0 = (unsigned)f2bf((f[0] + bias) * mk[0]) |
                                    ((unsigned)f2bf((f[1] + bias) * mk[1]) << 16);
            const unsigned int q1 = (unsigned)f2bf((f[2] + bias) * mk[2]) |
                                    ((unsigned)f2bf((f[3] + bias) * mk[3]) << 16);
            *(uint2*)(dst + (r * 32 + h) * 128 + s0) = make_uint2(q0, q1);
        }
    }
}

// ---------------------------------------------------------------------------
// k2: WG = 4x4 (i,j) pairs. Stage2: 128x128x128 MFMA GEMM (frags direct from
// global). Accum -> P_lds[16][1032] bf16 (k2''-layout, b64 conflict-free).
// Stage3: [16 x 128 x 1024] MFMA vs w_out_t; epilogue (+b_out)*inv_norm.
// ---------------------------------------------------------------------------
__global__ __launch_bounds__(256) void k2_main(
    const unsigned short* __restrict__ a_t,
    const unsigned short* __restrict__ b_t,
    const unsigned short* __restrict__ w_out_t,
    const float* __restrict__ inv_norm,
    const float* __restrict__ b_out,
    float* __restrict__ out) {
    __shared__ unsigned short P[16 * 1032];   // 33 KB, row stride 1032 (+8 pad)
    const int ib = blockIdx.x, jb = blockIdx.y;
    const int tid = threadIdx.x;
    const int w = tid >> 6, l = tid & 63;
    const int quad = l >> 4, l15 = l & 15;
    const int wm = w >> 1, wn = w & 1;

    v4f acc[4][4];
    const v4f z4 = {0.f, 0.f, 0.f, 0.f};
    for (int a = 0; a < 4; ++a)
        for (int bn = 0; bn < 4; ++bn) acc[a][bn] = z4;

    // stage 2: C[ih][jk] += A[ih][s] * B[s][jk], K = 128
    const unsigned short* arow = a_t + (ib * 128 + wm * 64 + l15) * 128;
    const unsigned short* brow = b_t + (jb * 128 + wn * 64 + l15) * 128;
    for (int kb = 0; kb < 4; ++kb) {
        const int ks = kb * 32 + quad * 8;
        v8s af[4], bfr[4];
        for (int tm = 0; tm < 4; ++tm)
            af[tm] = *(const v8s*)(arow + tm * 16 * 128 + ks);
        for (int tn = 0; tn < 4; ++tn)
            bfr[tn] = *(const v8s*)(brow + tn * 16 * 128 + ks);
        for (int tm = 0; tm < 4; ++tm)
            for (int tn = 0; tn < 4; ++tn)
                acc[tm][tn] = __builtin_amdgcn_mfma_f32_16x16x32_bf16(
                    af[tm], bfr[tn], acc[tm][tn], 0, 0, 0);
    }

    // accum -> P_lds: pair = iL*4+jL, element k2'' = hg*128 + k*4 + hr
    for (int tm = 0; tm < 4; ++tm) {
        const int row_ih = wm * 64 + tm * 16 + quad * 4;
        const int iL = row_ih >> 5;
        const int hg = (row_ih & 31) >> 2;
        for (int tn = 0; tn < 4; ++tn) {
            const int col_jk = wn * 64 + tn * 16 + l15;
            const int jL = col_jk >> 5, k = col_jk & 31;
            const int pair = iL * 4 + jL;
            const v4f f = acc[tm][tn];
            const unsigned int q0 = (unsigned)f2bf(f[0]) | ((unsigned)f2bf(f[1]) << 16);
            const unsigned int q1 = (unsigned)f2bf(f[2]) | ((unsigned)f2bf(f[3]) << 16);
            *(uint2*)(&P[pair * 1032 + (hg * 32 + k) * 4]) = make_uint2(q0, q1);
        }
    }
    __syncthreads();

    // stage 3: D[pair][z] = P[pair][k2''] * w_out_t[z][k2''], K = 1024
    v4f acc3[2] = {z4, z4};
    for (int kb2 = 0; kb2 < 32; ++kb2) {
        const v8s pa = *(const v8s*)(&P[l15 * 1032 + (kb2 * 4 + quad) * 8]);
        for (int e = 0; e < 2; ++e) {
            const int z = (w * 2 + e) * 16 + l15;
            const v8s wb = *(const v8s*)(w_out_t + z * 1024 + kb2 * 32 + quad * 8);
            acc3[e] = __builtin_amdgcn_mfma_f32_16x16x32_bf16(pa, wb, acc3[e], 0, 0, 0);
        }
    }

    // epilogue: D row = pair = quad*4+u, col z
    for (int e = 0; e < 2; ++e) {
        const int z = (w * 2 + e) * 16 + l15;
        const float bo = b_out[z];
        for (int u = 0; u < 4; ++u) {
            const int pair = quad * 4 + u;
            const int gi = ib * 4 + (pair >> 2);
            const int gj = jb * 4 + (pair & 3);
            const float inv = inv_norm[gi * 256 + gj];
            out[(size_t)(gi * 256 + gj) * 128 + z] = (acc3[e][u] + bo) * inv;
        }
    }
}

extern "C" void kernel_launch(void* const* d_in, const int* in_sizes, int n_in,
                              void* d_out, int out_size, void* d_ws, size_t ws_size,
                              hipStream_t stream) {
    const float* m     = (const float*)d_in[0];
    const float* mask  = (const float*)d_in[1];
    const float* ln_w  = (const float*)d_in[2];
    const float* ln_b  = (const float*)d_in[3];
    const float* w1    = (const float*)d_in[4];
    const float* b1    = (const float*)d_in[5];
    const float* w2    = (const float*)d_in[6];
    const float* b2    = (const float*)d_in[7];
    const float* w_out = (const float*)d_in[8];
    const float* b_out = (const float*)d_in[9];
    float* out = (float*)d_out;

    unsigned short* a_t      = (unsigned short*)d_ws;      // 8192*128 bf16 = 2 MB
    unsigned short* b_t      = a_t + 8192 * 128;           // 2 MB
    unsigned short* w_out_t  = b_t + 8192 * 128;           // 128*1024 bf16 = 256 KB
    float*          inv_norm = (float*)(w_out_t + 128 * 1024); // 256 KB
    unsigned short* wt       = (unsigned short*)(inv_norm + 65536); // 32 KB

    k0_prep<<<256, 256, 0, stream>>>(mask, w1, w2, w_out, wt, w_out_t, inv_norm);
    k1_lnproj<<<256, 256, 0, stream>>>(m, mask, ln_w, ln_b, b1, b2, wt, a_t, b_t);
    k2_main<<<dim3(64, 64), 256, 0, stream>>>(a_t, b_t, w_out_t, inv_norm, b_out, out);
}

// Round 2
// 217.106 us; speedup vs baseline: 1.3474x; 1.3474x over previous
//
#include <hip/hip_runtime.h>
#include <hip/hip_bf16.h>

typedef short v8s __attribute__((ext_vector_type(8)));
typedef float v4f __attribute__((ext_vector_type(4)));
typedef float v16f __attribute__((ext_vector_type(16)));

#define LN_EPS 1e-5f
#define EPS_N 1e-3f

__device__ __forceinline__ unsigned short f2bf(float f) {
    __hip_bfloat16 h = __float2bfloat16(f);
    return __builtin_bit_cast(unsigned short, h);
}
__device__ __forceinline__ unsigned int pk2(float a, float b) {
    return (unsigned)f2bf(a) | ((unsigned)f2bf(b) << 16);
}

// ---------------------------------------------------------------------------
// k0: inv_norm[256][256], wt[64][256] (w1^T|w2^T bf16), w_out_t[128][1024] bf16
//     with permuted contraction index k2'' = (h/4)*128 + k*4 + (h%4)
// ---------------------------------------------------------------------------
__global__ __launch_bounds__(256) void k0_prep(
    const float* __restrict__ mask,
    const float* __restrict__ w1, const float* __restrict__ w2,
    const float* __restrict__ w_out,
    unsigned short* __restrict__ wt,
    unsigned short* __restrict__ w_out_t,
    float* __restrict__ inv_norm) {
    const int b = blockIdx.x, t = threadIdx.x;
    float acc = 0.f;
    for (int s = 0; s < 128; ++s)
        acc += mask[s * 256 + b] * mask[s * 256 + t];
    inv_norm[b * 256 + t] = 1.0f / (EPS_N + acc);
    for (int e2 = 0; e2 < 2; ++e2) {
        int e = b * 512 + e2 * 256 + t;
        int z = e >> 10, k2 = e & 1023;
        int hg = k2 >> 7, k = (k2 >> 2) & 31, hr = k2 & 3;
        int h = hg * 4 + hr;
        w_out_t[e] = f2bf(w_out[(h * 32 + k) * 128 + z]);
    }
    if (b == 0) {
        for (int e = t; e < 16384; e += 256) {
            int h2 = e >> 8, c = e & 255;
            float v = (h2 < 32) ? w1[c * 32 + h2] : w2[c * 32 + (h2 - 32)];
            wt[e] = f2bf(v);
        }
    }
}

// ---------------------------------------------------------------------------
// k1: WG = (r, s-half): 64 s-rows. Prefetch all rows, LN, MFMA 64x64x256,
// epilogue (+bias)*mask -> a_t[r*32+h][s], b_t[r*32+h][s] bf16.
// ---------------------------------------------------------------------------
__global__ __launch_bounds__(256, 2) void k1_lnproj(
    const float* __restrict__ m, const float* __restrict__ mask,
    const float* __restrict__ ln_w, const float* __restrict__ ln_b,
    const float* __restrict__ b1, const float* __restrict__ b2,
    const unsigned short* __restrict__ wt,
    unsigned short* __restrict__ a_t, unsigned short* __restrict__ b_t) {
    __shared__ unsigned short mh[64 * 256];   // 32 KB, chunk-swizzled
    const int r = blockIdx.x, sh = blockIdx.y;
    const int tid = threadIdx.x;
    const int w = tid >> 6, l = tid & 63;
    const int quad = l >> 4, l15 = l & 15;

    const float4 lwv = *(const float4*)(ln_w + l * 4);
    const float4 lbv = *(const float4*)(ln_b + l * 4);

    // phase 1: wave w owns local rows w*16 .. w*16+15. Prefetch all 16 first.
    const int sg0 = sh * 64 + w * 16;
    float4 v[16];
    #pragma unroll
    for (int it = 0; it < 16; ++it)
        v[it] = *(const float4*)(m + (size_t)((sg0 + it) * 256 + r) * 256 + (l << 2));
    #pragma unroll
    for (int it = 0; it < 16; ++it) {
        const float4 x = v[it];
        float sum = x.x + x.y + x.z + x.w;
        float sq  = x.x * x.x + x.y * x.y + x.z * x.z + x.w * x.w;
        for (int off = 32; off; off >>= 1) {
            sum += __shfl_xor(sum, off);
            sq  += __shfl_xor(sq,  off);
        }
        const float mu   = sum * (1.f / 256.f);
        const float var  = sq * (1.f / 256.f) - mu * mu;
        const float rstd = rsqrtf(var + LN_EPS);
        const unsigned int p0 = pk2((x.x - mu) * rstd * lwv.x + lbv.x,
                                    (x.y - mu) * rstd * lwv.y + lbv.y);
        const unsigned int p1 = pk2((x.z - mu) * rstd * lwv.z + lbv.z,
                                    (x.w - mu) * rstd * lwv.w + lbv.w);
        const int sl = w * 16 + it;
        const int addr = sl * 256 + (((l >> 1) ^ (sl & 31)) << 3) + ((l & 1) << 2);
        *(uint2*)(&mh[addr]) = make_uint2(p0, p1);
    }
    __syncthreads();

    // phase 2: wave w -> m-tile w (rows w*16..w*16+15), n-tiles 0..3
    v4f acc[4];
    const v4f z4 = {0.f, 0.f, 0.f, 0.f};
    for (int tn = 0; tn < 4; ++tn) acc[tn] = z4;

    const int row = w * 16 + l15;
    #pragma unroll
    for (int kb = 0; kb < 8; ++kb) {
        const v8s af = *(const v8s*)(&mh[row * 256 + (((kb * 4 + quad) ^ (row & 31)) << 3)]);
        #pragma unroll
        for (int tn = 0; tn < 4; ++tn) {
            const v8s bf = *(const v8s*)(wt + (tn * 16 + l15) * 256 + kb * 32 + quad * 8);
            acc[tn] = __builtin_amdgcn_mfma_f32_16x16x32_bf16(af, bf, acc[tn], 0, 0, 0);
        }
    }

    // epilogue: rows s = sh*64 + w*16 + quad*4 + u, col h2 = tn*16+l15
    const int s0 = sh * 64 + w * 16 + quad * 4;
    float mk[4];
    #pragma unroll
    for (int u = 0; u < 4; ++u) mk[u] = mask[(s0 + u) * 256 + r];
    #pragma unroll
    for (int tn = 0; tn < 4; ++tn) {
        const int h2 = tn * 16 + l15;
        const float bias = (h2 < 32) ? b1[h2] : b2[h2 - 32];
        unsigned short* dst = (h2 < 32) ? a_t : b_t;
        const int h = h2 & 31;
        const v4f f = acc[tn];
        const unsigned int q0 = pk2((f[0] + bias) * mk[0], (f[1] + bias) * mk[1]);
        const unsigned int q1 = pk2((f[2] + bias) * mk[2], (f[3] + bias) * mk[3]);
        *(uint2*)(dst + (r * 32 + h) * 128 + s0) = make_uint2(q0, q1);
    }
}

// ---------------------------------------------------------------------------
// k2: 256 WGs x 512 thr (8 waves), 1 WG/CU. Each WG: persistent w_out frags
// (wave = (zh, kq): 64 z x 256 k2'' in 128 VGPRs), then 8 pair-blocks of
// 32 pairs (4i x 8j). Per block: stage2 = 128x256x128 GEMM (32x32x16 MFMA,
// global b128 loads) -> P LDS (64 KB, XOR-swizzled, conflict-free);
// stage3 = 32x128x1024 GEMM, LDS A-reads + register B; 4-way kq reduction
// through LDS; fused epilogue (+b_out)*inv_norm.
// ---------------------------------------------------------------------------
__global__ __launch_bounds__(512, 2) void k2_main(
    const unsigned short* __restrict__ a_t,
    const unsigned short* __restrict__ b_t,
    const unsigned short* __restrict__ w_out_t,
    const float* __restrict__ inv_norm,
    const float* __restrict__ b_out,
    float* __restrict__ out) {
    __shared__ __align__(16) unsigned char smem[65536];
    unsigned short* P = (unsigned short*)smem;   // [32 pairs][1024 k2''] swizzled
    float* red = (float*)smem;                   // [8 waves][32 p][32 l31][2 e]

    const int g = blockIdx.x;
    const int ib = g >> 2;                 // 0..63  (4 i's)
    const int jb0 = (g & 3) * 8;           // j-block start
    const int tid = threadIdx.x;
    const int w = tid >> 6;                // 0..7
    const int l = tid & 63;
    const int l31 = l & 31;
    const int half = l >> 5;

    // stage-2 roles: wave = (wm 0..1, wn 0..3)
    const int wm = w >> 2, wn = w & 3;
    // stage-3 roles: wave = (zh 0..1, kq 0..3)
    const int zh = w >> 2, kq = w & 3;

    // persistent w_out fragments: z = zh*64 + e*32 + l31, ksteps t = kq*16+tl
    v8s wfr[16][2];
    #pragma unroll
    for (int tl = 0; tl < 16; ++tl) {
        const int t = kq * 16 + tl;
        #pragma unroll
        for (int e = 0; e < 2; ++e) {
            const int z = zh * 64 + e * 32 + l31;
            wfr[tl][e] = *(const v8s*)(w_out_t + z * 1024 + t * 16 + half * 8);
        }
    }
    const float bo0 = b_out[zh * 64 + l31];
    const float bo1 = b_out[zh * 64 + 32 + l31];

    const v16f z16 = {0.f,0.f,0.f,0.f,0.f,0.f,0.f,0.f,0.f,0.f,0.f,0.f,0.f,0.f,0.f,0.f};

    for (int blk = 0; blk < 8; ++blk) {
        const int jb = jb0 + blk;
        // ---- stage 2: C[128 ih][256 jk], K=128 ----
        v16f acc2[2][2];
        acc2[0][0] = z16; acc2[0][1] = z16; acc2[1][0] = z16; acc2[1][1] = z16;
        const unsigned short* abase = a_t + (ib * 128 + wm * 64 + l31) * 128;
        const unsigned short* bbase = b_t + (jb * 256 + wn * 64 + l31) * 128;
        #pragma unroll
        for (int kb = 0; kb < 8; ++kb) {
            const int ko = kb * 16 + half * 8;
            const v8s a0 = *(const v8s*)(abase + ko);
            const v8s a1 = *(const v8s*)(abase + 32 * 128 + ko);
            const v8s b0 = *(const v8s*)(bbase + ko);
            const v8s b1v = *(const v8s*)(bbase + 32 * 128 + ko);
            acc2[0][0] = __builtin_amdgcn_mfma_f32_32x32x16_bf16(a0, b0,  acc2[0][0], 0, 0, 0);
            acc2[0][1] = __builtin_amdgcn_mfma_f32_32x32x16_bf16(a0, b1v, acc2[0][1], 0, 0, 0);
            acc2[1][0] = __builtin_amdgcn_mfma_f32_32x32x16_bf16(a1, b0,  acc2[1][0], 0, 0, 0);
            acc2[1][1] = __builtin_amdgcn_mfma_f32_32x32x16_bf16(a1, b1v, acc2[1][1], 0, 0, 0);
        }
        // ---- P write: pair p = iL*8+jL; k2'' = (2q+half)*128 + 4k + u ----
        #pragma unroll
        for (int mi = 0; mi < 2; ++mi) {
            #pragma unroll
            for (int ni = 0; ni < 2; ++ni) {
                const int p = (2 * wm + mi) * 8 + (2 * wn + ni);
                const int esw = 2 * (p & 15);
                const v16f f = acc2[mi][ni];
                #pragma unroll
                for (int q = 0; q < 4; ++q) {
                    const unsigned int lo = pk2(f[4 * q + 0], f[4 * q + 1]);
                    const unsigned int hi = pk2(f[4 * q + 2], f[4 * q + 3]);
                    const int u8 = (2 * q + half) * 32 + l31;
                    *(uint2*)(P + p * 1024 + ((u8 ^ esw) << 2)) = make_uint2(lo, hi);
                }
            }
        }
        __syncthreads();

        // ---- stage 3: D[32 p][z], K-quarter kq; A from LDS, B from regs ----
        v16f acc3[2];
        acc3[0] = z16; acc3[1] = z16;
        #pragma unroll
        for (int tl = 0; tl < 16; ++tl) {
            const int t = kq * 16 + tl;
            const int u8 = t * 4 + half * 2;
            const v8s pa = *(const v8s*)(P + l31 * 1024 + ((u8 ^ (2 * (l31 & 15))) << 2));
            acc3[0] = __builtin_amdgcn_mfma_f32_32x32x16_bf16(pa, wfr[tl][0], acc3[0], 0, 0, 0);
            acc3[1] = __builtin_amdgcn_mfma_f32_32x32x16_bf16(pa, wfr[tl][1], acc3[1], 0, 0, 0);
        }
        __syncthreads();   // P fully consumed -> safe to overlay red

        // ---- write partials: red[w][p][l31][e] ----
        #pragma unroll
        for (int q = 0; q < 4; ++q) {
            #pragma unroll
            for (int u = 0; u < 4; ++u) {
                const int rr = 4 * q + u;
                const int p = u + 8 * q + 4 * half;
                float2 pr = make_float2(acc3[0][rr], acc3[1][rr]);
                *(float2*)(red + w * 2048 + p * 64 + l31 * 2) = pr;
            }
        }
        __syncthreads();

        // ---- epilogue: wave w sums 4 kq partials for slice (zh, pq=w&3) ----
        const int pq = w & 3;
        #pragma unroll
        for (int pi = 0; pi < 4; ++pi) {
            const int p = pq * 8 + half * 4 + pi;
            const int gi = ib * 4 + (p >> 3);
            const int gj = jb * 8 + (p & 7);
            const float inv = inv_norm[gi * 256 + gj];
            float s0 = 0.f, s1 = 0.f;
            #pragma unroll
            for (int k2 = 0; k2 < 4; ++k2) {
                const float2 pr = *(const float2*)(red + (zh * 4 + k2) * 2048 + p * 64 + l31 * 2);
                s0 += pr.x; s1 += pr.y;
            }
            float* ob = out + (size_t)(gi * 256 + gj) * 128 + zh * 64;
            ob[l31]      = (s0 + bo0) * inv;
            ob[32 + l31] = (s1 + bo1) * inv;
        }
        __syncthreads();   // red consumed before next block's P writes
    }
}

extern "C" void kernel_launch(void* const* d_in, const int* in_sizes, int n_in,
                              void* d_out, int out_size, void* d_ws, size_t ws_size,
                              hipStream_t stream) {
    const float* m     = (const float*)d_in[0];
    const float* mask  = (const float*)d_in[1];
    const float* ln_w  = (const float*)d_in[2];
    const float* ln_b  = (const float*)d_in[3];
    const float* w1    = (const float*)d_in[4];
    const float* b1    = (const float*)d_in[5];
    const float* w2    = (const float*)d_in[6];
    const float* b2    = (const float*)d_in[7];
    const float* w_out = (const float*)d_in[8];
    const float* b_out = (const float*)d_in[9];
    float* out = (float*)d_out;

    unsigned short* a_t      = (unsigned short*)d_ws;          // 2 MB
    unsigned short* b_t      = a_t + 8192 * 128;               // 2 MB
    unsigned short* w_out_t  = b_t + 8192 * 128;               // 256 KB
    float*          inv_norm = (float*)(w_out_t + 128 * 1024); // 256 KB
    unsigned short* wt       = (unsigned short*)(inv_norm + 65536); // 32 KB

    k0_prep<<<256, 256, 0, stream>>>(mask, w1, w2, w_out, wt, w_out_t, inv_norm);
    k1_lnproj<<<dim3(256, 2), 256, 0, stream>>>(m, mask, ln_w, ln_b, b1, b2, wt, a_t, b_t);
    k2_main<<<256, 512, 0, stream>>>(a_t, b_t, w_out_t, inv_norm, b_out, out);
}

// Round 3
// 199.774 us; speedup vs baseline: 1.4643x; 1.0868x over previous
//
#include <hip/hip_runtime.h>
#include <hip/hip_bf16.h>

typedef short v8s __attribute__((ext_vector_type(8)));
typedef float v4f __attribute__((ext_vector_type(4)));
typedef float v16f __attribute__((ext_vector_type(16)));

#define LN_EPS 1e-5f
#define EPS_N 1e-3f

__device__ __forceinline__ unsigned short f2bf(float f) {
    __hip_bfloat16 h = __float2bfloat16(f);
    return __builtin_bit_cast(unsigned short, h);
}
__device__ __forceinline__ unsigned int pk2(float a, float b) {
    return (unsigned)f2bf(a) | ((unsigned)f2bf(b) << 16);
}

// ---------------------------------------------------------------------------
// Fragment-linear layouts (element index, 2B elems):
//   a_f/b_f:  ((tile*8 + kb)*64 + lane)*8 + e   tile=R>>5 (R=r*32+h), lane=half*32+(R&31),
//             k = kb*16 + half*8 + e            -> k2 stage2 loads are lane-contiguous b128
//   w_out_f:  ((t*4 + zt)*64 + lane)*8 + e8     t=k2''>>4, zt=z>>5, lane=half*32+(z&31),
//             k2'' = t*16 + half*8 + e8         (k2'' = (h/4)*128 + k*4 + (h%4))
// ---------------------------------------------------------------------------

__global__ __launch_bounds__(256) void k0_prep(
    const float* __restrict__ mask,
    const float* __restrict__ w1, const float* __restrict__ w2,
    const float* __restrict__ w_out,
    unsigned short* __restrict__ wt,
    unsigned short* __restrict__ w_out_f,
    float* __restrict__ inv_norm) {
    const int b = blockIdx.x, t = threadIdx.x;
    float acc = 0.f;
    for (int s = 0; s < 128; ++s)
        acc += mask[s * 256 + b] * mask[s * 256 + t];
    inv_norm[b * 256 + t] = 1.0f / (EPS_N + acc);
    // w_out_f in fragment-linear order
    for (int e2 = 0; e2 < 2; ++e2) {
        const int d = b * 512 + e2 * 256 + t;
        const int e8 = d & 7, l31v = (d >> 3) & 31, halfv = (d >> 8) & 1;
        const int zt = (d >> 9) & 3, tt = d >> 11;
        const int k2 = tt * 16 + halfv * 8 + e8;
        const int z = zt * 32 + l31v;
        const int hg = k2 >> 7, k = (k2 >> 2) & 31, hr = k2 & 3;
        const int h = hg * 4 + hr;
        w_out_f[d] = f2bf(w_out[(h * 32 + k) * 128 + z]);
    }
    if (b == 0) {
        for (int e = t; e < 16384; e += 256) {
            int h2 = e >> 8, c = e & 255;
            float v = (h2 < 32) ? w1[c * 32 + h2] : w2[c * 32 + (h2 - 32)];
            wt[e] = f2bf(v);
        }
    }
}

// ---------------------------------------------------------------------------
// k1: WG = (r, s-half): 64 s-rows. LN in 2 batches of 8 rows, MFMA 64x64x256,
// epilogue (+bias)*mask -> a_f/b_f in fragment-linear layout.
// ---------------------------------------------------------------------------
__global__ __launch_bounds__(256, 2) void k1_lnproj(
    const float* __restrict__ m, const float* __restrict__ mask,
    const float* __restrict__ ln_w, const float* __restrict__ ln_b,
    const float* __restrict__ b1, const float* __restrict__ b2,
    const unsigned short* __restrict__ wt,
    unsigned short* __restrict__ a_f, unsigned short* __restrict__ b_f) {
    __shared__ unsigned short mh[64 * 256];   // 32 KB, chunk-swizzled
    const int r = blockIdx.x, sh = blockIdx.y;
    const int tid = threadIdx.x;
    const int w = tid >> 6, l = tid & 63;
    const int quad = l >> 4, l15 = l & 15;

    const float4 lwv = *(const float4*)(ln_w + l * 4);
    const float4 lbv = *(const float4*)(ln_b + l * 4);

    const int sg0 = sh * 64 + w * 16;
    for (int bb = 0; bb < 2; ++bb) {
        float4 v[8];
        #pragma unroll
        for (int it = 0; it < 8; ++it)
            v[it] = *(const float4*)(m + (size_t)((sg0 + bb * 8 + it) * 256 + r) * 256 + (l << 2));
        #pragma unroll
        for (int it = 0; it < 8; ++it) {
            const float4 x = v[it];
            float sum = x.x + x.y + x.z + x.w;
            float sq  = x.x * x.x + x.y * x.y + x.z * x.z + x.w * x.w;
            for (int off = 32; off; off >>= 1) {
                sum += __shfl_xor(sum, off);
                sq  += __shfl_xor(sq,  off);
            }
            const float mu   = sum * (1.f / 256.f);
            const float var  = sq * (1.f / 256.f) - mu * mu;
            const float rstd = rsqrtf(var + LN_EPS);
            const unsigned int p0 = pk2((x.x - mu) * rstd * lwv.x + lbv.x,
                                        (x.y - mu) * rstd * lwv.y + lbv.y);
            const unsigned int p1 = pk2((x.z - mu) * rstd * lwv.z + lbv.z,
                                        (x.w - mu) * rstd * lwv.w + lbv.w);
            const int sl = w * 16 + bb * 8 + it;
            const int addr = sl * 256 + (((l >> 1) ^ (sl & 31)) << 3) + ((l & 1) << 2);
            *(uint2*)(&mh[addr]) = make_uint2(p0, p1);
        }
    }
    __syncthreads();

    v4f acc[4];
    const v4f z4 = {0.f, 0.f, 0.f, 0.f};
    for (int tn = 0; tn < 4; ++tn) acc[tn] = z4;

    const int row = w * 16 + l15;
    #pragma unroll
    for (int kb = 0; kb < 8; ++kb) {
        const v8s af = *(const v8s*)(&mh[row * 256 + (((kb * 4 + quad) ^ (row & 31)) << 3)]);
        #pragma unroll
        for (int tn = 0; tn < 4; ++tn) {
            const v8s bf = *(const v8s*)(wt + (tn * 16 + l15) * 256 + kb * 32 + quad * 8);
            acc[tn] = __builtin_amdgcn_mfma_f32_16x16x32_bf16(af, bf, acc[tn], 0, 0, 0);
        }
    }

    // epilogue: s0..s0+3 at rows h2; write into fragment-linear a_f/b_f
    const int s0 = sh * 64 + w * 16 + quad * 4;
    const int kb_s = s0 >> 4, half_s = (s0 >> 3) & 1, e0 = s0 & 7;
    float mk[4];
    #pragma unroll
    for (int u = 0; u < 4; ++u) mk[u] = mask[(s0 + u) * 256 + r];
    #pragma unroll
    for (int tn = 0; tn < 4; ++tn) {
        const int h2 = tn * 16 + l15;
        const float bias = (h2 < 32) ? b1[h2] : b2[h2 - 32];
        unsigned short* dst = (h2 < 32) ? a_f : b_f;
        const int h = h2 & 31;
        const v4f f = acc[tn];
        const unsigned int q0 = pk2((f[0] + bias) * mk[0], (f[1] + bias) * mk[1]);
        const unsigned int q1 = pk2((f[2] + bias) * mk[2], (f[3] + bias) * mk[3]);
        const int addr = ((r * 8 + kb_s) * 64 + half_s * 32 + h) * 8 + e0;
        *(uint2*)(dst + addr) = make_uint2(q0, q1);
    }
}

// ---------------------------------------------------------------------------
// k2: 256 WGs x 512 thr, 1 WG/CU. Persistent w_out frags (128 VGPR/wave),
// 8 pair-blocks of 32 pairs. Stage2: coalesced fragment-linear b128 loads,
// 32x32x16 MFMA -> P LDS (64 KB swizzled). Stage3: LDS A + register B,
// kq-split; reduction in a DISJOINT 64 KB LDS region (2 barriers/block).
// Epilogue: (+b_out)*inv_norm with nontemporal stores (keep L2 clean).
// ---------------------------------------------------------------------------
__global__ __launch_bounds__(512, 2) void k2_main(
    const unsigned short* __restrict__ a_f,
    const unsigned short* __restrict__ b_f,
    const unsigned short* __restrict__ w_out_f,
    const float* __restrict__ inv_norm,
    const float* __restrict__ b_out,
    float* __restrict__ out) {
    __shared__ __align__(16) unsigned char smem[131072];
    unsigned short* P = (unsigned short*)smem;           // [32][1024] swizzled, 64 KB
    float* red = (float*)(smem + 65536);                 // [8 waves][32 p][32][2], 64 KB

    const int g = blockIdx.x;
    const int ib = g >> 2;
    const int jb0 = (g & 3) * 8;
    const int tid = threadIdx.x;
    const int w = tid >> 6;
    const int l = tid & 63;
    const int l31 = l & 31;
    const int half = l >> 5;

    const int wm = w >> 2, wn = w & 3;     // stage-2 roles
    const int zh = w >> 2, kq = w & 3;     // stage-3 roles

    // persistent w_out fragments: coalesced b128 loads
    v8s wfr[16][2];
    #pragma unroll
    for (int tl = 0; tl < 16; ++tl) {
        const int t = kq * 16 + tl;
        #pragma unroll
        for (int e = 0; e < 2; ++e)
            wfr[tl][e] = *(const v8s*)(w_out_f + (t * 4 + zh * 2 + e) * 512 + l * 8);
    }
    const float bo0 = b_out[zh * 64 + l31];
    const float bo1 = b_out[zh * 64 + 32 + l31];

    const v16f z16 = {0.f,0.f,0.f,0.f,0.f,0.f,0.f,0.f,0.f,0.f,0.f,0.f,0.f,0.f,0.f,0.f};
    const unsigned short* ab = a_f + (size_t)((ib * 4 + wm * 2) * 8) * 512 + l * 8;

    for (int blk = 0; blk < 8; ++blk) {
        const int jb = jb0 + blk;
        // ---- stage 2: coalesced fragment loads + MFMA ----
        v16f acc2[2][2];
        acc2[0][0] = z16; acc2[0][1] = z16; acc2[1][0] = z16; acc2[1][1] = z16;
        const unsigned short* bb = b_f + (size_t)((jb * 8 + wn * 2) * 8) * 512 + l * 8;
        #pragma unroll
        for (int kb = 0; kb < 8; ++kb) {
            const v8s a0 = *(const v8s*)(ab + kb * 512);
            const v8s a1 = *(const v8s*)(ab + (8 + kb) * 512);
            const v8s b0 = *(const v8s*)(bb + kb * 512);
            const v8s b1v = *(const v8s*)(bb + (8 + kb) * 512);
            acc2[0][0] = __builtin_amdgcn_mfma_f32_32x32x16_bf16(a0, b0,  acc2[0][0], 0, 0, 0);
            acc2[0][1] = __builtin_amdgcn_mfma_f32_32x32x16_bf16(a0, b1v, acc2[0][1], 0, 0, 0);
            acc2[1][0] = __builtin_amdgcn_mfma_f32_32x32x16_bf16(a1, b0,  acc2[1][0], 0, 0, 0);
            acc2[1][1] = __builtin_amdgcn_mfma_f32_32x32x16_bf16(a1, b1v, acc2[1][1], 0, 0, 0);
        }
        // ---- P write (XOR-swizzled, conflict-free) ----
        #pragma unroll
        for (int mi = 0; mi < 2; ++mi) {
            #pragma unroll
            for (int ni = 0; ni < 2; ++ni) {
                const int p = (2 * wm + mi) * 8 + (2 * wn + ni);
                const int esw = 2 * (p & 15);
                const v16f f = acc2[mi][ni];
                #pragma unroll
                for (int q = 0; q < 4; ++q) {
                    const unsigned int lo = pk2(f[4 * q + 0], f[4 * q + 1]);
                    const unsigned int hi = pk2(f[4 * q + 2], f[4 * q + 3]);
                    const int u8 = (2 * q + half) * 32 + l31;
                    *(uint2*)(P + p * 1024 + ((u8 ^ esw) << 2)) = make_uint2(lo, hi);
                }
            }
        }
        __syncthreads();   // barrier 1: P visible

        // ---- stage 3: LDS A-reads + register B ----
        v16f acc3[2];
        acc3[0] = z16; acc3[1] = z16;
        #pragma unroll
        for (int tl = 0; tl < 16; ++tl) {
            const int t = kq * 16 + tl;
            const int u8 = t * 4 + half * 2;
            const v8s pa = *(const v8s*)(P + l31 * 1024 + ((u8 ^ (2 * (l31 & 15))) << 2));
            acc3[0] = __builtin_amdgcn_mfma_f32_32x32x16_bf16(pa, wfr[tl][0], acc3[0], 0, 0, 0);
            acc3[1] = __builtin_amdgcn_mfma_f32_32x32x16_bf16(pa, wfr[tl][1], acc3[1], 0, 0, 0);
        }
        // ---- partials into disjoint red region (no barrier needed) ----
        #pragma unroll
        for (int q = 0; q < 4; ++q) {
            #pragma unroll
            for (int u = 0; u < 4; ++u) {
                const int rr = 4 * q + u;
                const int p = u + 8 * q + 4 * half;
                *(float2*)(red + w * 2048 + p * 64 + l31 * 2) =
                    make_float2(acc3[0][rr], acc3[1][rr]);
            }
        }
        __syncthreads();   // barrier 2: red visible (also covers P-reads done)

        // ---- epilogue: 4-way kq reduction + (+b_out)*inv_norm, NT stores ----
        const int pq = w & 3;
        #pragma unroll
        for (int pi = 0; pi < 4; ++pi) {
            const int p = pq * 8 + half * 4 + pi;
            const int gi = ib * 4 + (p >> 3);
            const int gj = jb * 8 + (p & 7);
            const float inv = inv_norm[gi * 256 + gj];
            float s0 = 0.f, s1 = 0.f;
            #pragma unroll
            for (int k2 = 0; k2 < 4; ++k2) {
                const float2 pr = *(const float2*)(red + (zh * 4 + k2) * 2048 + p * 64 + l31 * 2);
                s0 += pr.x; s1 += pr.y;
            }
            float* ob = out + (size_t)(gi * 256 + gj) * 128 + zh * 64;
            __builtin_nontemporal_store((s0 + bo0) * inv, ob + l31);
            __builtin_nontemporal_store((s1 + bo1) * inv, ob + 32 + l31);
        }
        // next block's P-writes wait on barrier 1; red-reads are done before it
    }
}

extern "C" void kernel_launch(void* const* d_in, const int* in_sizes, int n_in,
                              void* d_out, int out_size, void* d_ws, size_t ws_size,
                              hipStream_t stream) {
    const float* m     = (const float*)d_in[0];
    const float* mask  = (const float*)d_in[1];
    const float* ln_w  = (const float*)d_in[2];
    const float* ln_b  = (const float*)d_in[3];
    const float* w1    = (const float*)d_in[4];
    const float* b1    = (const float*)d_in[5];
    const float* w2    = (const float*)d_in[6];
    const float* b2    = (const float*)d_in[7];
    const float* w_out = (const float*)d_in[8];
    const float* b_out = (const float*)d_in[9];
    float* out = (float*)d_out;

    unsigned short* a_f      = (unsigned short*)d_ws;          // 2 MB
    unsigned short* b_f      = a_f + 8192 * 128;               // 2 MB
    unsigned short* w_out_f  = b_f + 8192 * 128;               // 256 KB
    float*          inv_norm = (float*)(w_out_f + 128 * 1024); // 256 KB
    unsigned short* wt       = (unsigned short*)(inv_norm + 65536); // 32 KB

    k0_prep<<<256, 256, 0, stream>>>(mask, w1, w2, w_out, wt, w_out_f, inv_norm);
    k1_lnproj<<<dim3(256, 2), 256, 0, stream>>>(m, mask, ln_w, ln_b, b1, b2, wt, a_f, b_f);
    k2_main<<<256, 512, 0, stream>>>(a_f, b_f, w_out_f, inv_norm, b_out, out);
}